// Round 15
// baseline (412.049 us; speedup 1.0000x reference)
//
#include <hip/hip_runtime.h>
#include <hip/hip_bf16.h>

#define NN 50000
#define EE 1000000
#define NGRAPHS 64
#define NB_N 196        // (NN+255)/256
#define NB_E 3907       // (EE+255)/256
#define NB_X 3125       // NN*16/256
#define NB_T 1563       // (NN+31)/32 node-tile blocks
#define NTAB 4096
#define SPL 16          // reduction splits per graph

#define INV_SQRT_NEIGH 0.22360679774997896f   // 1/sqrt(20)
#define INV_SQRT_NODES 0.035777087639996634f  // 1/sqrt(781.25)
#define SQRT3 1.7320508075688772f
#define BSCALE 2.8234621879136734f            // sqrt(10)/1.12
#define BSTEP 0.3888888888888889f             // 3.5/9
#define INV_BSTEP 2.5714285714285716f
#define PI_F 3.14159265358979323846f
#define TAB_DR (3.5f / 4095.0f)
#define TAB_SCALE (4095.0f / 3.5f)

__device__ __forceinline__ float silu_f(float x) { return x / (1.0f + __expf(-x)); }
__device__ __forceinline__ float sigm_f(float x) { return 1.0f / (1.0f + __expf(-x)); }

__device__ __forceinline__ unsigned short f2bf(float f) {
    union { float f; unsigned u; } v; v.f = f;
    unsigned r = v.u + 0x7fffu + ((v.u >> 16) & 1u);
    return (unsigned short)(r >> 16);
}
__device__ __forceinline__ unsigned pk2(float a, float b) {
    return (unsigned)f2bf(a) | ((unsigned)f2bf(b) << 16);
}
__device__ __forceinline__ float bflo(unsigned u) { return __uint_as_float(u << 16); }
__device__ __forceinline__ float bfhi(unsigned u) { return __uint_as_float(u & 0xffff0000u); }

// ================= combined prologue =================
// blocks [0,NTAB): radial tables (block per entry);
// [NTAB, NTAB+NB_N): graph bounds; then degree hist; then x->bf16
__global__ __launch_bounds__(256) void k_pre3(
    const float* __restrict__ fc1w0, const float* __restrict__ fc1w1,
    const float* __restrict__ fc2w0, const float* __restrict__ fc2w1,
    const float* __restrict__ fcow0, const float* __restrict__ fcow1,
    float* __restrict__ tab1, float* __restrict__ tab2f,
    unsigned short* __restrict__ tab3b,
    const int* __restrict__ batch, int* __restrict__ gstart,
    const int* __restrict__ ei, int* __restrict__ deg,
    const float* __restrict__ x, unsigned short* __restrict__ row0)
{
    int blk = blockIdx.x;
    int t = threadIdx.x;
    if (blk < NTAB) {
        __shared__ float h[3][100];
        int entry = blk;
        float r = entry * TAB_DR;
        float b[10];
#pragma unroll
        for (int i = 0; i < 10; ++i) {
            float d = (r - (float)i * BSTEP) * INV_BSTEP;
            b[i] = __expf(-d * d) * BSCALE;
        }
        for (int job = t; job < 300; job += 256) {
            int tb = job / 100;
            int j = job - tb * 100;
            const float* w0 = (tb == 0) ? fc1w0 : (tb == 1 ? fc2w0 : fcow0);
            float a = 0.0f;
#pragma unroll
            for (int i = 0; i < 10; ++i) a += b[i] * w0[i * 100 + j];
            h[tb][j] = silu_f(a);
        }
        __syncthreads();
        if (t < 32) {
            float acc = 0.0f;
            for (int j = 0; j < 100; ++j) acc += h[0][j] * fc1w1[j * 32 + t];
            tab1[(size_t)entry * 32 + t] = acc;
        } else if (t < 192) {
            int o = t - 32;
            float acc = 0.0f;
            for (int j = 0; j < 100; ++j) acc += h[1][j] * fc2w1[j * 160 + o];
            tab2f[((size_t)entry * 32 + (o & 31)) * 8 + (o >> 5)] = acc;
        } else {
            int o = t - 192;
            float acc = 0.0f;
            for (int j = 0; j < 100; ++j) acc += h[2][j] * fcow1[j * 64 + o];
            tab3b[((size_t)entry * 32 + (o & 31)) * 2 + (o >> 5)] = f2bf(acc);
        }
    } else if (blk < NTAB + NB_N) {
        int n = (blk - NTAB) * 256 + t;
        if (n >= NN) return;
        int b = batch[n];
        if (n == 0) { for (int g = 0; g <= b; ++g) gstart[g] = 0; }
        else {
            int pb = batch[n - 1];
            for (int g = pb + 1; g <= b; ++g) gstart[g] = n;
        }
        if (n == NN - 1) { for (int g = b + 1; g <= NGRAPHS; ++g) gstart[g] = NN; }
    } else if (blk < NTAB + NB_N + NB_E) {
        int e = (blk - NTAB - NB_N) * 256 + t;
        if (e < EE) atomicAdd(&deg[ei[EE + e]], 1);
    } else {
        int idx = (blk - NTAB - NB_N - NB_E) * 256 + t;
        if (idx < NN * 16) row0[idx] = f2bf(x[idx]);
    }
}

// ================= CSR scans =================
__global__ __launch_bounds__(256) void k_scan1(const int* __restrict__ deg, int* __restrict__ bsum)
{
    __shared__ int sd[256];
    int t = threadIdx.x;
    int i = blockIdx.x * 256 + t;
    sd[t] = (i < NN) ? deg[i] : 0;
    __syncthreads();
#pragma unroll
    for (int o = 128; o > 0; o >>= 1) {
        if (t < o) sd[t] += sd[t + o];
        __syncthreads();
    }
    if (t == 0) bsum[blockIdx.x] = sd[0];
}

__global__ void k_scan2(const int* __restrict__ bsum, int* __restrict__ boff, int* __restrict__ rowp)
{
    if (threadIdx.x == 0) {
        int acc = 0;
        for (int b = 0; b < NB_N; ++b) { boff[b] = acc; acc += bsum[b]; }
        rowp[NN] = EE;
    }
}

__global__ __launch_bounds__(256) void k_scan3(
    const int* __restrict__ deg, const int* __restrict__ boff,
    int* __restrict__ rowp, int* __restrict__ cursor)
{
    __shared__ int sd[256];
    int t = threadIdx.x;
    int i = blockIdx.x * 256 + t;
    int v = (i < NN) ? deg[i] : 0;
    sd[t] = v;
    __syncthreads();
#pragma unroll
    for (int o = 1; o < 256; o <<= 1) {
        int xv = 0;
        if (t >= o) xv = sd[t - o];
        __syncthreads();
        sd[t] += xv;
        __syncthreads();
    }
    if (i < NN) {
        int val = boff[blockIdx.x] + sd[t] - v;   // exclusive
        rowp[i] = val;
        cursor[i] = val;
    }
}

// ---- geometry once per edge, 16B record scattered to dst-sorted slot ----
__global__ __launch_bounds__(256) void k_geom(
    const float* __restrict__ pos, const int* __restrict__ ei,
    const float* __restrict__ eshift, const float* __restrict__ lat,
    const int* __restrict__ batch, int* __restrict__ cursor,
    uint4* __restrict__ rec)
{
    int e = blockIdx.x * 256 + threadIdx.x;
    if (e >= EE) return;
    int src = ei[e];
    int dst = ei[EE + e];
    int g = batch[src];
    const float* L = lat + g * 9;
    float t0 = eshift[e*3+0], t1 = eshift[e*3+1], t2 = eshift[e*3+2];
    float vx = pos[dst*3+0] - pos[src*3+0] + t0*L[0] + t1*L[3] + t2*L[6];
    float vy = pos[dst*3+1] - pos[src*3+1] + t0*L[1] + t1*L[4] + t2*L[7];
    float vz = pos[dst*3+2] - pos[src*3+2] + t0*L[2] + t1*L[5] + t2*L[8];
    float r = sqrtf(vx*vx + vy*vy + vz*vz);
    float u = 2.0f * (r * (1.0f/3.5f) - 1.0f);
    float cut;
    if (u > 0.0f) cut = 0.0f;
    else if (u < -2.0f) cut = 1.0f;
    else cut = 0.5f * (1.0f - __cosf(PI_F * u));
    float inv = 1.0f / fmaxf(r, 1e-12f);
    float sc = SQRT3 * cut * inv;
    int i0 = (int)fminf(r * TAB_SCALE + 0.5f, 4095.0f);
    int slot = atomicAdd(&cursor[dst], 1);
    rec[slot] = make_uint4(pk2(sc * vx, sc * vy), pk2(sc * vz, 0.0f),
                           (unsigned)src | ((unsigned)i0 << 17),
                           __float_as_uint(cut));
}

#define EREC_DECODE(E)                                  \
    float cs_ = __uint_as_float((E).w);                 \
    float cx_ = bflo((E).x);                            \
    float cy_ = bfhi((E).x);                            \
    float cz_ = bflo((E).y);                            \
    int src_ = (int)((E).z & 0x1ffffu);                 \
    int i0_ = (int)((E).z >> 17);

// ================= fused node-centric edge kernels (1 wave = 1 dst node) =================
#define F1_EDGE(E, ACC) {                                           \
    EREC_DECODE(E)                                                  \
    float w_ = tab1[(size_t)i0_ * 32 + toff];                       \
    float xs_ = __uint_as_float((unsigned)row0[src_ * 16 + c] << 16); \
    float gs_ = (q == 0) ? cs_ : (q == 1 ? cx_ : (q == 2 ? cy_ : cz_)); \
    ACC += w_ * xs_ * gs_; }

__global__ __launch_bounds__(256) void k_fuse1(
    const int* __restrict__ rowp, const uint4* __restrict__ rec,
    const float* __restrict__ tab1, const unsigned short* __restrict__ row0,
    float* __restrict__ a1)
{
    int wid = (blockIdx.x * 256 + threadIdx.x) >> 6;
    int l = threadIdx.x & 63;
    if (wid >= NN) return;
    int b0 = __builtin_amdgcn_readfirstlane(rowp[wid]);
    int b1 = __builtin_amdgcn_readfirstlane(rowp[wid + 1]);
    int q = l >> 4, c = l & 15;
    int toff = (q ? 16 : 0) + c;
    float aA = 0.0f, aB = 0.0f, aC = 0.0f, aD = 0.0f;
    int s = b0;
    for (; s + 3 < b1; s += 4) {
        uint4 eA = rec[s], eB = rec[s+1], eC = rec[s+2], eD = rec[s+3];
        F1_EDGE(eA, aA) F1_EDGE(eB, aB) F1_EDGE(eC, aC) F1_EDGE(eD, aD)
    }
    for (; s < b1; ++s) {
        uint4 eA = rec[s];
        F1_EDGE(eA, aA)
    }
    a1[(size_t)wid * 64 + l] = (aA + aB) + (aC + aD);
}

// layer 2: fp32 weight rows tab2f[entry][32][8] -> float4 + float, zero decode
#define F2_EDGE(E, AS, AX, AY, AZ) {                                \
    EREC_DECODE(E)                                                  \
    const float* tp_ = tab2f + ((size_t)i0_ * 32 + c) * 8;          \
    float4 w14_ = *(const float4*)tp_;                              \
    float w5_ = tp_[4];                                             \
    uint2 rv_ = ((const uint2*)row1)[(size_t)src_ * 32 + c];        \
    float sv_ = bflo(rv_.x), vx_ = bfhi(rv_.x);                     \
    float vy_ = bflo(rv_.y), vz_ = bfhi(rv_.y);                     \
    float dot_ = vx_ * cx_ + vy_ * cy_ + vz_ * cz_;                 \
    float w3s_ = w14_.z * sv_, w4c_ = w14_.w * cs_;                 \
    AS += w14_.x * sv_ * cs_ + w14_.y * dot_;                       \
    AX += w3s_ * cx_ + w4c_ * vx_ + w5_ * (vy_ * cz_ - vz_ * cy_);  \
    AY += w3s_ * cy_ + w4c_ * vy_ + w5_ * (vz_ * cx_ - vx_ * cz_);  \
    AZ += w3s_ * cz_ + w4c_ * vz_ + w5_ * (vx_ * cy_ - vy_ * cx_); }

__global__ __launch_bounds__(256) void k_fuse2(
    const int* __restrict__ rowp, const uint4* __restrict__ rec,
    const float* __restrict__ tab2f, const unsigned short* __restrict__ row1,
    float* __restrict__ a2)
{
    int wid = (blockIdx.x * 256 + threadIdx.x) >> 6;
    int l = threadIdx.x & 63;
    if (wid >= NN) return;
    int b0 = __builtin_amdgcn_readfirstlane(rowp[wid]);
    int b1 = __builtin_amdgcn_readfirstlane(rowp[wid + 1]);
    int p = l >> 5, c = l & 31;
    float s0 = 0, x0 = 0, y0 = 0, z0 = 0;
    float s1a = 0, x1 = 0, y1 = 0, z1 = 0;
    int s = b0 + p;
    for (; s + 6 < b1; s += 8) {
        uint4 eA = rec[s], eB = rec[s+2], eC = rec[s+4], eD = rec[s+6];
        F2_EDGE(eA, s0, x0, y0, z0)
        F2_EDGE(eB, s1a, x1, y1, z1)
        F2_EDGE(eC, s0, x0, y0, z0)
        F2_EDGE(eD, s1a, x1, y1, z1)
    }
    for (; s < b1; s += 2) {
        uint4 eA = rec[s];
        F2_EDGE(eA, s1a, x1, y1, z1)
    }
    float mS = s0 + s1a, mX = x0 + x1, mY = y0 + y1, mZ = z0 + z1;
    mS += __shfl_xor(mS, 32);
    mX += __shfl_xor(mX, 32);
    mY += __shfl_xor(mY, 32);
    mZ += __shfl_xor(mZ, 32);
    if (p == 0) {
        float* ap = a2 + (size_t)wid * 128;
        ap[c]      = mS;
        ap[32 + c] = mX;
        ap[64 + c] = mY;
        ap[96 + c] = mZ;
    }
}

#define F3_EDGE(E, ACC) {                                           \
    EREC_DECODE(E)                                                  \
    unsigned tv_ = ((const unsigned*)tab3b)[(size_t)i0_ * 32 + c];  \
    uint2 rv_ = ((const uint2*)row2)[(size_t)src_ * 32 + c];        \
    float w1_ = bflo(tv_), w2_ = bfhi(tv_);                         \
    float sv_ = bflo(rv_.x), vx_ = bfhi(rv_.x);                     \
    float vy_ = bflo(rv_.y), vz_ = bfhi(rv_.y);                     \
    float dot_ = vx_ * cx_ + vy_ * cy_ + vz_ * cz_;                 \
    ACC += w1_ * sv_ * cs_ + w2_ * dot_; }

__global__ __launch_bounds__(256) void k_fuse3(
    const int* __restrict__ rowp, const uint4* __restrict__ rec,
    const unsigned short* __restrict__ tab3b, const unsigned short* __restrict__ row2,
    float* __restrict__ a3)
{
    int wid = (blockIdx.x * 256 + threadIdx.x) >> 6;
    int l = threadIdx.x & 63;
    if (wid >= NN) return;
    int b0 = __builtin_amdgcn_readfirstlane(rowp[wid]);
    int b1 = __builtin_amdgcn_readfirstlane(rowp[wid + 1]);
    int p = l >> 5, c = l & 31;
    float aA = 0.0f, aB = 0.0f;
    int s = b0 + p;
    for (; s + 6 < b1; s += 8) {
        uint4 eA = rec[s], eB = rec[s+2], eC = rec[s+4], eD = rec[s+6];
        F3_EDGE(eA, aA) F3_EDGE(eB, aB) F3_EDGE(eC, aA) F3_EDGE(eD, aB)
    }
    for (; s < b1; s += 2) {
        uint4 eA = rec[s];
        F3_EDGE(eA, aA)
    }
    float acc = aA + aB;
    acc += __shfl_xor(acc, 32);
    if (p == 0) a3[(size_t)wid * 32 + c] = acc;
}

// ================= node kernels: LDS-tiled, 32 nodes/block, 8 thr/node =================
// a1 layout per node (64 floats): [ms 16][mvx 16][mvy 16][mvz 16]
__global__ __launch_bounds__(256) void k_node1(
    const float* __restrict__ x, const float* __restrict__ z,
    const float* __restrict__ a1,
    const float* __restrict__ sc1, const float* __restrict__ lin1s,
    const float* __restrict__ lin1v,
    ushort4* __restrict__ row1)
{
    __shared__ float xz[32][20];
    __shared__ float am[32][68];
    __shared__ float shb[32][68];
    int t = threadIdx.x;
    int base = blockIdx.x * 32;
    if (t < 128) {
        int node = t >> 2, rem = t & 3;
        if (base + node < NN)
            *(float4*)&xz[node][rem * 4] = ((const float4*)x)[(size_t)(base + node) * 4 + rem];
    }
#pragma unroll
    for (int k = 0; k < 2; ++k) {
        int f = k * 256 + t;
        int node = f >> 4, rem = f & 15;
        if (base + node < NN)
            *(float4*)&am[node][rem * 4] = ((const float4*)a1)[(size_t)(base + node) * 16 + rem];
    }
    __syncthreads();
    int node = t >> 3, og = t & 7;
    int gnode = base + node;
    float zz = (gnode < NN) ? z[gnode] : 0.0f;
    int o0 = og * 8;
    float acc[8];
#pragma unroll
    for (int k = 0; k < 8; ++k) acc[k] = 0.0f;
#pragma unroll
    for (int c = 0; c < 16; ++c) {
        float xc = xz[node][c] * zz;
        float ac = am[node][c] * INV_SQRT_NEIGH;
        float4 wa = *(const float4*)&sc1[c * 64 + o0];
        float4 wb = *(const float4*)&sc1[c * 64 + o0 + 4];
        float4 la = *(const float4*)&lin1s[c * 64 + o0];
        float4 lb = *(const float4*)&lin1s[c * 64 + o0 + 4];
        acc[0] += xc * wa.x + ac * la.x;
        acc[1] += xc * wa.y + ac * la.y;
        acc[2] += xc * wa.z + ac * la.z;
        acc[3] += xc * wa.w + ac * la.w;
        acc[4] += xc * wb.x + ac * lb.x;
        acc[5] += xc * wb.y + ac * lb.y;
        acc[6] += xc * wb.z + ac * lb.z;
        acc[7] += xc * wb.w + ac * lb.w;
    }
#pragma unroll
    for (int k = 0; k < 8; ++k) shb[node][o0 + k] = acc[k];
    __syncthreads();
    int o0v = og * 4;
    float a4[3][4];
#pragma unroll
    for (int i = 0; i < 3; ++i)
#pragma unroll
        for (int k = 0; k < 4; ++k) a4[i][k] = 0.0f;
#pragma unroll
    for (int c = 0; c < 16; ++c) {
        float4 lv = *(const float4*)&lin1v[c * 32 + o0v];
#pragma unroll
        for (int i = 0; i < 3; ++i) {
            float av = am[node][16 + i * 16 + c] * INV_SQRT_NEIGH;
            a4[i][0] += av * lv.x; a4[i][1] += av * lv.y;
            a4[i][2] += av * lv.z; a4[i][3] += av * lv.w;
        }
    }
    if (gnode < NN) {
#pragma unroll
        for (int k = 0; k < 4; ++k) {
            float so = silu_f(shb[node][o0v + k]);
            float gt = sigm_f(shb[node][32 + o0v + k]);
            row1[(size_t)gnode * 32 + o0v + k] =
                make_ushort4(f2bf(so), f2bf(a4[0][k] * gt), f2bf(a4[1][k] * gt), f2bf(a4[2][k] * gt));
        }
    }
}

// a2 layout per node (128 floats): [ms 32][mvx 32][mvy 32][mvz 32]
__global__ __launch_bounds__(256) void k_node2(
    const float* __restrict__ z,
    const uint2* __restrict__ row1, const float* __restrict__ a2,
    const float* __restrict__ sc2s, const float* __restrict__ sc2v,
    const float* __restrict__ lin2s, const float* __restrict__ lin2v,
    float* __restrict__ s2, ushort4* __restrict__ row2)
{
    __shared__ uint2 rw[32][33];
    __shared__ float am[32][132];
    __shared__ float shb[32][68];
    int t = threadIdx.x;
    int base = blockIdx.x * 32;
    {
        int node = t >> 3, rem = t & 7;
        if (base + node < NN) {
            const uint2* rp = row1 + (size_t)(base + node) * 32;
#pragma unroll
            for (int k = 0; k < 4; ++k)
                rw[node][rem * 4 + k] = rp[rem * 4 + k];
        }
    }
#pragma unroll
    for (int k = 0; k < 4; ++k) {
        int f = k * 256 + t;
        int node = f >> 5, rem = f & 31;
        if (base + node < NN)
            *(float4*)&am[node][rem * 4] = ((const float4*)a2)[(size_t)(base + node) * 32 + rem];
    }
    __syncthreads();
    int node = t >> 3, og = t & 7;
    int gnode = base + node;
    float zz = (gnode < NN) ? z[gnode] : 0.0f;
    int o0 = og * 8;
    float acc[8];
#pragma unroll
    for (int k = 0; k < 8; ++k) acc[k] = 0.0f;
#pragma unroll 8
    for (int c = 0; c < 32; ++c) {
        float sv = bflo(rw[node][c].x) * zz;
        float ac = am[node][c] * INV_SQRT_NEIGH;
        float4 wa = *(const float4*)&sc2s[c * 64 + o0];
        float4 wb = *(const float4*)&sc2s[c * 64 + o0 + 4];
        float4 la = *(const float4*)&lin2s[c * 64 + o0];
        float4 lb = *(const float4*)&lin2s[c * 64 + o0 + 4];
        acc[0] += sv * wa.x + ac * la.x;
        acc[1] += sv * wa.y + ac * la.y;
        acc[2] += sv * wa.z + ac * la.z;
        acc[3] += sv * wa.w + ac * la.w;
        acc[4] += sv * wb.x + ac * lb.x;
        acc[5] += sv * wb.y + ac * lb.y;
        acc[6] += sv * wb.z + ac * lb.z;
        acc[7] += sv * wb.w + ac * lb.w;
    }
#pragma unroll
    for (int k = 0; k < 8; ++k) shb[node][o0 + k] = acc[k];
    __syncthreads();
    int o0v = og * 4;
    float a4[3][4];
#pragma unroll
    for (int i = 0; i < 3; ++i)
#pragma unroll
        for (int k = 0; k < 4; ++k) a4[i][k] = 0.0f;
#pragma unroll 8
    for (int c = 0; c < 32; ++c) {
        float4 wv = *(const float4*)&sc2v[c * 32 + o0v];
        float4 lv = *(const float4*)&lin2v[c * 32 + o0v];
        uint2 rv = rw[node][c];
        float vvv[3];
        vvv[0] = bfhi(rv.x); vvv[1] = bflo(rv.y); vvv[2] = bfhi(rv.y);
#pragma unroll
        for (int i = 0; i < 3; ++i) {
            float av = am[node][32 + i * 32 + c] * INV_SQRT_NEIGH;
            a4[i][0] += vvv[i] * wv.x + av * lv.x;
            a4[i][1] += vvv[i] * wv.y + av * lv.y;
            a4[i][2] += vvv[i] * wv.z + av * lv.z;
            a4[i][3] += vvv[i] * wv.w + av * lv.w;
        }
    }
    if (gnode < NN) {
#pragma unroll
        for (int k = 0; k < 4; ++k) {
            float so = silu_f(shb[node][o0v + k]);
            float gt = sigm_f(shb[node][32 + o0v + k]);
            s2[gnode * 32 + o0v + k] = so;
            row2[(size_t)gnode * 32 + o0v + k] =
                make_ushort4(f2bf(so), f2bf(a4[0][k] * gt), f2bf(a4[1][k] * gt), f2bf(a4[2][k] * gt));
        }
    }
}

// ---- output stage 1: per-(graph,split) partial sums of [s2*z | a3] ----
__global__ __launch_bounds__(256) void k_red(
    const float* __restrict__ z, const int* __restrict__ gstart,
    const float* __restrict__ s2, const float* __restrict__ a3,
    float* __restrict__ pbuf)
{
    int g  = blockIdx.x >> 4;      // / SPL
    int sp = blockIdx.x & (SPL - 1);
    int n0 = gstart[g], n1 = gstart[g + 1];
    int per = (n1 - n0 + SPL - 1) / SPL;
    int a = n0 + sp * per;
    int b = a + per; if (b > n1) b = n1;
    int t = threadIdx.x;
    int comp = t & 63;
    int lane = t >> 6;
    float acc = 0.0f;
    for (int n = a + lane; n < b; n += 4) {
        if (comp < 32) acc += s2[n * 32 + comp] * z[n];
        else           acc += a3[(size_t)n * 32 + (comp - 32)];
    }
    __shared__ float sd[256];
    sd[t] = acc;
    __syncthreads();
    if (t < 64)
        pbuf[(size_t)blockIdx.x * 64 + t] = sd[t] + sd[t + 64] + sd[t + 128] + sd[t + 192];
}

// ---- output stage 2: fold partials + (64,32)@(32,100) GEMM ----
__global__ __launch_bounds__(128) void k_out2(
    const float* __restrict__ pbuf, const float* __restrict__ sco,
    const float* __restrict__ lino, float* __restrict__ out)
{
    __shared__ float A[32], B[32];
    int g = blockIdx.x;
    int t = threadIdx.x;
    if (t < 64) {
        float v = 0.0f;
        for (int sp = 0; sp < SPL; ++sp)
            v += pbuf[(size_t)(g * SPL + sp) * 64 + t];
        if (t < 32) A[t] = v;
        else        B[t - 32] = v * INV_SQRT_NEIGH;
    }
    __syncthreads();
    if (t < 100) {
        float res = 0.0f;
#pragma unroll
        for (int c = 0; c < 32; ++c)
            res += A[c] * sco[c * 100 + t] + B[c] * lino[c * 100 + t];
        out[g * 100 + t] = res * INV_SQRT_NODES;
    }
}

// ================= launcher =================
extern "C" void kernel_launch(void* const* d_in, const int* in_sizes, int n_in,
                              void* d_out, int out_size, void* d_ws, size_t ws_size,
                              hipStream_t stream)
{
    const float* pos   = (const float*)d_in[0];
    const float* x     = (const float*)d_in[1];
    const float* z     = (const float*)d_in[2];
    const int*   ei    = (const int*)d_in[3];
    const float* esh   = (const float*)d_in[4];
    const float* lat   = (const float*)d_in[5];
    const int*   batch = (const int*)d_in[6];
    const float* fc1w0 = (const float*)d_in[7];
    const float* fc1w1 = (const float*)d_in[8];
    const float* sc1   = (const float*)d_in[9];
    const float* lin1s = (const float*)d_in[10];
    const float* lin1v = (const float*)d_in[11];
    const float* fc2w0 = (const float*)d_in[12];
    const float* fc2w1 = (const float*)d_in[13];
    const float* sc2s  = (const float*)d_in[14];
    const float* sc2v  = (const float*)d_in[15];
    const float* lin2s = (const float*)d_in[16];
    const float* lin2v = (const float*)d_in[17];
    const float* fcow0 = (const float*)d_in[18];
    const float* fcow1 = (const float*)d_in[19];
    const float* sco   = (const float*)d_in[20];
    const float* lino  = (const float*)d_in[21];
    float* out = (float*)d_out;

    char* cur = (char*)d_ws;
    auto alloc = [&](size_t bytes) { char* r = cur; cur += (bytes + 15) & ~(size_t)15; return r; };

    float* a1    = (float*)alloc((size_t)NN * 64 * 4);
    float* a2    = (float*)alloc((size_t)NN * 128 * 4);
    float* a3    = (float*)alloc((size_t)NN * 32 * 4);
    float* s2    = (float*)alloc((size_t)NN * 32 * 4);
    unsigned short* row0 = (unsigned short*)alloc((size_t)NN * 16 * 2);
    ushort4* row1 = (ushort4*)alloc((size_t)NN * 32 * 8);
    ushort4* row2 = (ushort4*)alloc((size_t)NN * 32 * 8);
    float* tab1  = (float*)alloc((size_t)NTAB * 32 * 4);
    float* tab2f = (float*)alloc((size_t)NTAB * 32 * 8 * 4);
    unsigned short* tab3b = (unsigned short*)alloc((size_t)NTAB * 32 * 2 * 2);
    float* pbuf  = (float*)alloc((size_t)NGRAPHS * SPL * 64 * 4);
    int* deg     = (int*)alloc((size_t)NN * 4);
    int* rowp    = (int*)alloc((size_t)(NN + 4) * 4);
    int* cursor  = (int*)alloc((size_t)NN * 4);
    int* bsum    = (int*)alloc(256 * 4);
    int* boff    = (int*)alloc(256 * 4);
    int* gstart  = (int*)alloc(68 * 4);
    uint4* rec   = (uint4*)alloc((size_t)EE * 16);

    (void)hipMemsetAsync(deg, 0, (size_t)NN * 4, stream);

    k_pre3<<<NTAB + NB_N + NB_E + NB_X, 256, 0, stream>>>(
        fc1w0, fc1w1, fc2w0, fc2w1, fcow0, fcow1, tab1, tab2f, tab3b,
        batch, gstart, ei, deg, x, row0);

    k_scan1<<<NB_N, 256, 0, stream>>>(deg, bsum);
    k_scan2<<<1, 64, 0, stream>>>(bsum, boff, rowp);
    k_scan3<<<NB_N, 256, 0, stream>>>(deg, boff, rowp, cursor);
    k_geom <<<NB_E, 256, 0, stream>>>(pos, ei, esh, lat, batch, cursor, rec);

    int fb = (NN * 64 + 255) / 256;   // 1 wave per node
    k_fuse1<<<fb, 256, 0, stream>>>(rowp, rec, tab1, row0, a1);
    k_node1<<<NB_T, 256, 0, stream>>>(x, z, a1, sc1, lin1s, lin1v, row1);
    k_fuse2<<<fb, 256, 0, stream>>>(rowp, rec, tab2f, (const unsigned short*)row1, a2);
    k_node2<<<NB_T, 256, 0, stream>>>(z, (const uint2*)row1, a2, sc2s, sc2v, lin2s, lin2v, s2, row2);
    k_fuse3<<<fb, 256, 0, stream>>>(rowp, rec, tab3b, (const unsigned short*)row2, a3);
    k_red<<<NGRAPHS * SPL, 256, 0, stream>>>(z, gstart, s2, a3, pbuf);
    k_out2<<<NGRAPHS, 128, 0, stream>>>(pbuf, sco, lino, out);
}

// Round 16
// 360.465 us; speedup vs baseline: 1.1431x; 1.1431x over previous
//
#include <hip/hip_runtime.h>
#include <hip/hip_bf16.h>

#define NN 50000
#define EE 1000000
#define NGRAPHS 64
#define NB_N 196        // (NN+255)/256
#define NB_E 3907       // (EE+255)/256
#define NB_X 3125       // NN*16/256
#define NB_T 1563       // (NN+31)/32 node-tile blocks
#define NTAB 4096
#define SPL 16          // reduction splits per graph

#define INV_SQRT_NEIGH 0.22360679774997896f   // 1/sqrt(20)
#define INV_SQRT_NODES 0.035777087639996634f  // 1/sqrt(781.25)
#define SQRT3 1.7320508075688772f
#define BSCALE 2.8234621879136734f            // sqrt(10)/1.12
#define BSTEP 0.3888888888888889f             // 3.5/9
#define INV_BSTEP 2.5714285714285716f
#define PI_F 3.14159265358979323846f
#define TAB_DR (3.5f / 4095.0f)
#define TAB_SCALE (4095.0f / 3.5f)

__device__ __forceinline__ float silu_f(float x) { return x / (1.0f + __expf(-x)); }
__device__ __forceinline__ float sigm_f(float x) { return 1.0f / (1.0f + __expf(-x)); }

__device__ __forceinline__ unsigned short f2bf(float f) {
    union { float f; unsigned u; } v; v.f = f;
    unsigned r = v.u + 0x7fffu + ((v.u >> 16) & 1u);
    return (unsigned short)(r >> 16);
}
__device__ __forceinline__ unsigned pk2(float a, float b) {
    return (unsigned)f2bf(a) | ((unsigned)f2bf(b) << 16);
}
__device__ __forceinline__ float bflo(unsigned u) { return __uint_as_float(u << 16); }
__device__ __forceinline__ float bfhi(unsigned u) { return __uint_as_float(u & 0xffff0000u); }

// ================= combined prologue =================
// blocks [0,NTAB): radial tables (block per entry);
// [NTAB, NTAB+NB_N): graph bounds; then degree hist; then x->bf16
__global__ __launch_bounds__(256) void k_pre3(
    const float* __restrict__ fc1w0, const float* __restrict__ fc1w1,
    const float* __restrict__ fc2w0, const float* __restrict__ fc2w1,
    const float* __restrict__ fcow0, const float* __restrict__ fcow1,
    float* __restrict__ tab1, unsigned short* __restrict__ tab2b,
    unsigned short* __restrict__ tab3b,
    const int* __restrict__ batch, int* __restrict__ gstart,
    const int* __restrict__ ei, int* __restrict__ deg,
    const float* __restrict__ x, unsigned short* __restrict__ row0)
{
    int blk = blockIdx.x;
    int t = threadIdx.x;
    if (blk < NTAB) {
        __shared__ float h[3][100];
        int entry = blk;
        float r = entry * TAB_DR;
        float b[10];
#pragma unroll
        for (int i = 0; i < 10; ++i) {
            float d = (r - (float)i * BSTEP) * INV_BSTEP;
            b[i] = __expf(-d * d) * BSCALE;
        }
        for (int job = t; job < 300; job += 256) {
            int tb = job / 100;
            int j = job - tb * 100;
            const float* w0 = (tb == 0) ? fc1w0 : (tb == 1 ? fc2w0 : fcow0);
            float a = 0.0f;
#pragma unroll
            for (int i = 0; i < 10; ++i) a += b[i] * w0[i * 100 + j];
            h[tb][j] = silu_f(a);
        }
        __syncthreads();
        if (t < 32) {
            float acc = 0.0f;
            for (int j = 0; j < 100; ++j) acc += h[0][j] * fc1w1[j * 32 + t];
            tab1[(size_t)entry * 32 + t] = acc;
        } else if (t < 192) {
            int o = t - 32;
            float acc = 0.0f;
            for (int j = 0; j < 100; ++j) acc += h[1][j] * fc2w1[j * 160 + o];
            tab2b[((size_t)entry * 32 + (o & 31)) * 8 + (o >> 5)] = f2bf(acc);
        } else {
            int o = t - 192;
            float acc = 0.0f;
            for (int j = 0; j < 100; ++j) acc += h[2][j] * fcow1[j * 64 + o];
            tab3b[((size_t)entry * 32 + (o & 31)) * 2 + (o >> 5)] = f2bf(acc);
        }
    } else if (blk < NTAB + NB_N) {
        int n = (blk - NTAB) * 256 + t;
        if (n >= NN) return;
        int b = batch[n];
        if (n == 0) { for (int g = 0; g <= b; ++g) gstart[g] = 0; }
        else {
            int pb = batch[n - 1];
            for (int g = pb + 1; g <= b; ++g) gstart[g] = n;
        }
        if (n == NN - 1) { for (int g = b + 1; g <= NGRAPHS; ++g) gstart[g] = NN; }
    } else if (blk < NTAB + NB_N + NB_E) {
        int e = (blk - NTAB - NB_N) * 256 + t;
        if (e < EE) atomicAdd(&deg[ei[EE + e]], 1);
    } else {
        int idx = (blk - NTAB - NB_N - NB_E) * 256 + t;
        if (idx < NN * 16) row0[idx] = f2bf(x[idx]);
    }
}

// ================= CSR scans =================
__global__ __launch_bounds__(256) void k_scan1(const int* __restrict__ deg, int* __restrict__ bsum)
{
    __shared__ int sd[256];
    int t = threadIdx.x;
    int i = blockIdx.x * 256 + t;
    sd[t] = (i < NN) ? deg[i] : 0;
    __syncthreads();
#pragma unroll
    for (int o = 128; o > 0; o >>= 1) {
        if (t < o) sd[t] += sd[t + o];
        __syncthreads();
    }
    if (t == 0) bsum[blockIdx.x] = sd[0];
}

__global__ void k_scan2(const int* __restrict__ bsum, int* __restrict__ boff, int* __restrict__ rowp)
{
    if (threadIdx.x == 0) {
        int acc = 0;
        for (int b = 0; b < NB_N; ++b) { boff[b] = acc; acc += bsum[b]; }
        rowp[NN] = EE;
    }
}

__global__ __launch_bounds__(256) void k_scan3(
    const int* __restrict__ deg, const int* __restrict__ boff,
    int* __restrict__ rowp, int* __restrict__ cursor)
{
    __shared__ int sd[256];
    int t = threadIdx.x;
    int i = blockIdx.x * 256 + t;
    int v = (i < NN) ? deg[i] : 0;
    sd[t] = v;
    __syncthreads();
#pragma unroll
    for (int o = 1; o < 256; o <<= 1) {
        int xv = 0;
        if (t >= o) xv = sd[t - o];
        __syncthreads();
        sd[t] += xv;
        __syncthreads();
    }
    if (i < NN) {
        int val = boff[blockIdx.x] + sd[t] - v;   // exclusive
        rowp[i] = val;
        cursor[i] = val;
    }
}

// ---- geometry once per edge, 16B record scattered to dst-sorted slot ----
__global__ __launch_bounds__(256) void k_geom(
    const float* __restrict__ pos, const int* __restrict__ ei,
    const float* __restrict__ eshift, const float* __restrict__ lat,
    const int* __restrict__ batch, int* __restrict__ cursor,
    uint4* __restrict__ rec)
{
    int e = blockIdx.x * 256 + threadIdx.x;
    if (e >= EE) return;
    int src = ei[e];
    int dst = ei[EE + e];
    int g = batch[src];
    const float* L = lat + g * 9;
    float t0 = eshift[e*3+0], t1 = eshift[e*3+1], t2 = eshift[e*3+2];
    float vx = pos[dst*3+0] - pos[src*3+0] + t0*L[0] + t1*L[3] + t2*L[6];
    float vy = pos[dst*3+1] - pos[src*3+1] + t0*L[1] + t1*L[4] + t2*L[7];
    float vz = pos[dst*3+2] - pos[src*3+2] + t0*L[2] + t1*L[5] + t2*L[8];
    float r = sqrtf(vx*vx + vy*vy + vz*vz);
    float u = 2.0f * (r * (1.0f/3.5f) - 1.0f);
    float cut;
    if (u > 0.0f) cut = 0.0f;
    else if (u < -2.0f) cut = 1.0f;
    else cut = 0.5f * (1.0f - __cosf(PI_F * u));
    float inv = 1.0f / fmaxf(r, 1e-12f);
    float sc = SQRT3 * cut * inv;
    int i0 = (int)fminf(r * TAB_SCALE + 0.5f, 4095.0f);
    int slot = atomicAdd(&cursor[dst], 1);
    rec[slot] = make_uint4(pk2(sc * vx, sc * vy), pk2(sc * vz, 0.0f),
                           (unsigned)src | ((unsigned)i0 << 17),
                           __float_as_uint(cut));
}

#define EREC_DECODE(E)                                  \
    float cs_ = __uint_as_float((E).w);                 \
    float cx_ = bflo((E).x);                            \
    float cy_ = bfhi((E).x);                            \
    float cz_ = bflo((E).y);                            \
    int src_ = (int)((E).z & 0x1ffffu);                 \
    int i0_ = (int)((E).z >> 17);

// ================= fused node-centric edge kernels (1 wave = 1 dst node) =================
#define F1_EDGE(E, ACC) {                                           \
    EREC_DECODE(E)                                                  \
    float w_ = tab1[(size_t)i0_ * 32 + toff];                       \
    float xs_ = __uint_as_float((unsigned)row0[src_ * 16 + c] << 16); \
    float gs_ = (q == 0) ? cs_ : (q == 1 ? cx_ : (q == 2 ? cy_ : cz_)); \
    ACC += w_ * xs_ * gs_; }

__global__ __launch_bounds__(256) void k_fuse1(
    const int* __restrict__ rowp, const uint4* __restrict__ rec,
    const float* __restrict__ tab1, const unsigned short* __restrict__ row0,
    float* __restrict__ a1)
{
    int wid = (blockIdx.x * 256 + threadIdx.x) >> 6;
    int l = threadIdx.x & 63;
    if (wid >= NN) return;
    int b0 = __builtin_amdgcn_readfirstlane(rowp[wid]);
    int b1 = __builtin_amdgcn_readfirstlane(rowp[wid + 1]);
    int q = l >> 4, c = l & 15;
    int toff = (q ? 16 : 0) + c;
    float aA = 0.0f, aB = 0.0f, aC = 0.0f, aD = 0.0f;
    int s = b0;
    for (; s + 3 < b1; s += 4) {
        uint4 eA = rec[s], eB = rec[s+1], eC = rec[s+2], eD = rec[s+3];
        F1_EDGE(eA, aA) F1_EDGE(eB, aB) F1_EDGE(eC, aC) F1_EDGE(eD, aD)
    }
    for (; s < b1; ++s) {
        uint4 eA = rec[s];
        F1_EDGE(eA, aA)
    }
    a1[(size_t)wid * 64 + l] = (aA + aB) + (aC + aD);
}

// layer 2: bf16 tab2b row fetched as ONE uint4 (round-14 config)
#define F2_EDGE(E, AS, AX, AY, AZ) {                                \
    EREC_DECODE(E)                                                  \
    uint4 tv_ = ((const uint4*)tab2b)[(size_t)i0_ * 32 + c];        \
    uint2 rv_ = ((const uint2*)row1)[(size_t)src_ * 32 + c];        \
    float w1_ = bflo(tv_.x), w2_ = bfhi(tv_.x);                     \
    float w3_ = bflo(tv_.y), w4_ = bfhi(tv_.y);                     \
    float w5_ = bflo(tv_.z);                                        \
    float sv_ = bflo(rv_.x), vx_ = bfhi(rv_.x);                     \
    float vy_ = bflo(rv_.y), vz_ = bfhi(rv_.y);                     \
    float dot_ = vx_ * cx_ + vy_ * cy_ + vz_ * cz_;                 \
    float w3s_ = w3_ * sv_, w4c_ = w4_ * cs_;                       \
    AS += w1_ * sv_ * cs_ + w2_ * dot_;                             \
    AX += w3s_ * cx_ + w4c_ * vx_ + w5_ * (vy_ * cz_ - vz_ * cy_);  \
    AY += w3s_ * cy_ + w4c_ * vy_ + w5_ * (vz_ * cx_ - vx_ * cz_);  \
    AZ += w3s_ * cz_ + w4c_ * vz_ + w5_ * (vx_ * cy_ - vy_ * cx_); }

__global__ __launch_bounds__(256) void k_fuse2(
    const int* __restrict__ rowp, const uint4* __restrict__ rec,
    const unsigned short* __restrict__ tab2b, const unsigned short* __restrict__ row1,
    float* __restrict__ a2)
{
    int wid = (blockIdx.x * 256 + threadIdx.x) >> 6;
    int l = threadIdx.x & 63;
    if (wid >= NN) return;
    int b0 = __builtin_amdgcn_readfirstlane(rowp[wid]);
    int b1 = __builtin_amdgcn_readfirstlane(rowp[wid + 1]);
    int p = l >> 5, c = l & 31;
    float s0 = 0, x0 = 0, y0 = 0, z0 = 0;
    float s1a = 0, x1 = 0, y1 = 0, z1 = 0;
    int s = b0 + p;
    for (; s + 4 < b1; s += 6) {
        uint4 eA = rec[s], eB = rec[s+2], eC = rec[s+4];
        F2_EDGE(eA, s0, x0, y0, z0)
        F2_EDGE(eB, s1a, x1, y1, z1)
        F2_EDGE(eC, s0, x0, y0, z0)
    }
    for (; s < b1; s += 2) {
        uint4 eA = rec[s];
        F2_EDGE(eA, s1a, x1, y1, z1)
    }
    float mS = s0 + s1a, mX = x0 + x1, mY = y0 + y1, mZ = z0 + z1;
    mS += __shfl_xor(mS, 32);
    mX += __shfl_xor(mX, 32);
    mY += __shfl_xor(mY, 32);
    mZ += __shfl_xor(mZ, 32);
    if (p == 0) {
        float* ap = a2 + (size_t)wid * 128;
        ap[c]      = mS;
        ap[32 + c] = mX;
        ap[64 + c] = mY;
        ap[96 + c] = mZ;
    }
}

#define F3_EDGE(E, ACC) {                                           \
    EREC_DECODE(E)                                                  \
    unsigned tv_ = ((const unsigned*)tab3b)[(size_t)i0_ * 32 + c];  \
    uint2 rv_ = ((const uint2*)row2)[(size_t)src_ * 32 + c];        \
    float w1_ = bflo(tv_), w2_ = bfhi(tv_);                         \
    float sv_ = bflo(rv_.x), vx_ = bfhi(rv_.x);                     \
    float vy_ = bflo(rv_.y), vz_ = bfhi(rv_.y);                     \
    float dot_ = vx_ * cx_ + vy_ * cy_ + vz_ * cz_;                 \
    ACC += w1_ * sv_ * cs_ + w2_ * dot_; }

__global__ __launch_bounds__(256) void k_fuse3(
    const int* __restrict__ rowp, const uint4* __restrict__ rec,
    const unsigned short* __restrict__ tab3b, const unsigned short* __restrict__ row2,
    float* __restrict__ a3)
{
    int wid = (blockIdx.x * 256 + threadIdx.x) >> 6;
    int l = threadIdx.x & 63;
    if (wid >= NN) return;
    int b0 = __builtin_amdgcn_readfirstlane(rowp[wid]);
    int b1 = __builtin_amdgcn_readfirstlane(rowp[wid + 1]);
    int p = l >> 5, c = l & 31;
    float aA = 0.0f, aB = 0.0f;
    int s = b0 + p;
    for (; s + 6 < b1; s += 8) {
        uint4 eA = rec[s], eB = rec[s+2], eC = rec[s+4], eD = rec[s+6];
        F3_EDGE(eA, aA) F3_EDGE(eB, aB) F3_EDGE(eC, aA) F3_EDGE(eD, aB)
    }
    for (; s < b1; s += 2) {
        uint4 eA = rec[s];
        F3_EDGE(eA, aA)
    }
    float acc = aA + aB;
    acc += __shfl_xor(acc, 32);
    if (p == 0) a3[(size_t)wid * 32 + c] = acc;
}

// ================= node kernels: LDS-tiled, 32 nodes/block, 8 thr/node =================
// a1 layout per node (64 floats): [ms 16][mvx 16][mvy 16][mvz 16]
__global__ __launch_bounds__(256) void k_node1(
    const float* __restrict__ x, const float* __restrict__ z,
    const float* __restrict__ a1,
    const float* __restrict__ sc1, const float* __restrict__ lin1s,
    const float* __restrict__ lin1v,
    ushort4* __restrict__ row1)
{
    __shared__ float xz[32][20];
    __shared__ float am[32][68];
    __shared__ float shb[32][68];
    int t = threadIdx.x;
    int base = blockIdx.x * 32;
    if (t < 128) {
        int node = t >> 2, rem = t & 3;
        if (base + node < NN)
            *(float4*)&xz[node][rem * 4] = ((const float4*)x)[(size_t)(base + node) * 4 + rem];
    }
#pragma unroll
    for (int k = 0; k < 2; ++k) {
        int f = k * 256 + t;
        int node = f >> 4, rem = f & 15;
        if (base + node < NN)
            *(float4*)&am[node][rem * 4] = ((const float4*)a1)[(size_t)(base + node) * 16 + rem];
    }
    __syncthreads();
    int node = t >> 3, og = t & 7;
    int gnode = base + node;
    float zz = (gnode < NN) ? z[gnode] : 0.0f;
    int o0 = og * 8;
    float acc[8];
#pragma unroll
    for (int k = 0; k < 8; ++k) acc[k] = 0.0f;
#pragma unroll
    for (int c = 0; c < 16; ++c) {
        float xc = xz[node][c] * zz;
        float ac = am[node][c] * INV_SQRT_NEIGH;
        float4 wa = *(const float4*)&sc1[c * 64 + o0];
        float4 wb = *(const float4*)&sc1[c * 64 + o0 + 4];
        float4 la = *(const float4*)&lin1s[c * 64 + o0];
        float4 lb = *(const float4*)&lin1s[c * 64 + o0 + 4];
        acc[0] += xc * wa.x + ac * la.x;
        acc[1] += xc * wa.y + ac * la.y;
        acc[2] += xc * wa.z + ac * la.z;
        acc[3] += xc * wa.w + ac * la.w;
        acc[4] += xc * wb.x + ac * lb.x;
        acc[5] += xc * wb.y + ac * lb.y;
        acc[6] += xc * wb.z + ac * lb.z;
        acc[7] += xc * wb.w + ac * lb.w;
    }
#pragma unroll
    for (int k = 0; k < 8; ++k) shb[node][o0 + k] = acc[k];
    __syncthreads();
    int o0v = og * 4;
    float a4[3][4];
#pragma unroll
    for (int i = 0; i < 3; ++i)
#pragma unroll
        for (int k = 0; k < 4; ++k) a4[i][k] = 0.0f;
#pragma unroll
    for (int c = 0; c < 16; ++c) {
        float4 lv = *(const float4*)&lin1v[c * 32 + o0v];
#pragma unroll
        for (int i = 0; i < 3; ++i) {
            float av = am[node][16 + i * 16 + c] * INV_SQRT_NEIGH;
            a4[i][0] += av * lv.x; a4[i][1] += av * lv.y;
            a4[i][2] += av * lv.z; a4[i][3] += av * lv.w;
        }
    }
    if (gnode < NN) {
#pragma unroll
        for (int k = 0; k < 4; ++k) {
            float so = silu_f(shb[node][o0v + k]);
            float gt = sigm_f(shb[node][32 + o0v + k]);
            row1[(size_t)gnode * 32 + o0v + k] =
                make_ushort4(f2bf(so), f2bf(a4[0][k] * gt), f2bf(a4[1][k] * gt), f2bf(a4[2][k] * gt));
        }
    }
}

// a2 layout per node (128 floats): [ms 32][mvx 32][mvy 32][mvz 32]
__global__ __launch_bounds__(256) void k_node2(
    const float* __restrict__ z,
    const uint2* __restrict__ row1, const float* __restrict__ a2,
    const float* __restrict__ sc2s, const float* __restrict__ sc2v,
    const float* __restrict__ lin2s, const float* __restrict__ lin2v,
    float* __restrict__ s2, ushort4* __restrict__ row2)
{
    __shared__ uint2 rw[32][33];
    __shared__ float am[32][132];
    __shared__ float shb[32][68];
    int t = threadIdx.x;
    int base = blockIdx.x * 32;
    {
        int node = t >> 3, rem = t & 7;
        if (base + node < NN) {
            const uint2* rp = row1 + (size_t)(base + node) * 32;
#pragma unroll
            for (int k = 0; k < 4; ++k)
                rw[node][rem * 4 + k] = rp[rem * 4 + k];
        }
    }
#pragma unroll
    for (int k = 0; k < 4; ++k) {
        int f = k * 256 + t;
        int node = f >> 5, rem = f & 31;
        if (base + node < NN)
            *(float4*)&am[node][rem * 4] = ((const float4*)a2)[(size_t)(base + node) * 32 + rem];
    }
    __syncthreads();
    int node = t >> 3, og = t & 7;
    int gnode = base + node;
    float zz = (gnode < NN) ? z[gnode] : 0.0f;
    int o0 = og * 8;
    float acc[8];
#pragma unroll
    for (int k = 0; k < 8; ++k) acc[k] = 0.0f;
#pragma unroll 8
    for (int c = 0; c < 32; ++c) {
        float sv = bflo(rw[node][c].x) * zz;
        float ac = am[node][c] * INV_SQRT_NEIGH;
        float4 wa = *(const float4*)&sc2s[c * 64 + o0];
        float4 wb = *(const float4*)&sc2s[c * 64 + o0 + 4];
        float4 la = *(const float4*)&lin2s[c * 64 + o0];
        float4 lb = *(const float4*)&lin2s[c * 64 + o0 + 4];
        acc[0] += sv * wa.x + ac * la.x;
        acc[1] += sv * wa.y + ac * la.y;
        acc[2] += sv * wa.z + ac * la.z;
        acc[3] += sv * wa.w + ac * la.w;
        acc[4] += sv * wb.x + ac * lb.x;
        acc[5] += sv * wb.y + ac * lb.y;
        acc[6] += sv * wb.z + ac * lb.z;
        acc[7] += sv * wb.w + ac * lb.w;
    }
#pragma unroll
    for (int k = 0; k < 8; ++k) shb[node][o0 + k] = acc[k];
    __syncthreads();
    int o0v = og * 4;
    float a4[3][4];
#pragma unroll
    for (int i = 0; i < 3; ++i)
#pragma unroll
        for (int k = 0; k < 4; ++k) a4[i][k] = 0.0f;
#pragma unroll 8
    for (int c = 0; c < 32; ++c) {
        float4 wv = *(const float4*)&sc2v[c * 32 + o0v];
        float4 lv = *(const float4*)&lin2v[c * 32 + o0v];
        uint2 rv = rw[node][c];
        float vvv[3];
        vvv[0] = bfhi(rv.x); vvv[1] = bflo(rv.y); vvv[2] = bfhi(rv.y);
#pragma unroll
        for (int i = 0; i < 3; ++i) {
            float av = am[node][32 + i * 32 + c] * INV_SQRT_NEIGH;
            a4[i][0] += vvv[i] * wv.x + av * lv.x;
            a4[i][1] += vvv[i] * wv.y + av * lv.y;
            a4[i][2] += vvv[i] * wv.z + av * lv.z;
            a4[i][3] += vvv[i] * wv.w + av * lv.w;
        }
    }
    if (gnode < NN) {
#pragma unroll
        for (int k = 0; k < 4; ++k) {
            float so = silu_f(shb[node][o0v + k]);
            float gt = sigm_f(shb[node][32 + o0v + k]);
            s2[gnode * 32 + o0v + k] = so;
            row2[(size_t)gnode * 32 + o0v + k] =
                make_ushort4(f2bf(so), f2bf(a4[0][k] * gt), f2bf(a4[1][k] * gt), f2bf(a4[2][k] * gt));
        }
    }
}

// ---- output stage 1: per-(graph,split) partial sums of [s2*z | a3] ----
__global__ __launch_bounds__(256) void k_red(
    const float* __restrict__ z, const int* __restrict__ gstart,
    const float* __restrict__ s2, const float* __restrict__ a3,
    float* __restrict__ pbuf)
{
    int g  = blockIdx.x >> 4;      // / SPL
    int sp = blockIdx.x & (SPL - 1);
    int n0 = gstart[g], n1 = gstart[g + 1];
    int per = (n1 - n0 + SPL - 1) / SPL;
    int a = n0 + sp * per;
    int b = a + per; if (b > n1) b = n1;
    int t = threadIdx.x;
    int comp = t & 63;
    int lane = t >> 6;
    float acc = 0.0f;
    for (int n = a + lane; n < b; n += 4) {
        if (comp < 32) acc += s2[n * 32 + comp] * z[n];
        else           acc += a3[(size_t)n * 32 + (comp - 32)];
    }
    __shared__ float sd[256];
    sd[t] = acc;
    __syncthreads();
    if (t < 64)
        pbuf[(size_t)blockIdx.x * 64 + t] = sd[t] + sd[t + 64] + sd[t + 128] + sd[t + 192];
}

// ---- output stage 2: fold partials + (64,32)@(32,100) GEMM ----
__global__ __launch_bounds__(128) void k_out2(
    const float* __restrict__ pbuf, const float* __restrict__ sco,
    const float* __restrict__ lino, float* __restrict__ out)
{
    __shared__ float A[32], B[32];
    int g = blockIdx.x;
    int t = threadIdx.x;
    if (t < 64) {
        float v = 0.0f;
        for (int sp = 0; sp < SPL; ++sp)
            v += pbuf[(size_t)(g * SPL + sp) * 64 + t];
        if (t < 32) A[t] = v;
        else        B[t - 32] = v * INV_SQRT_NEIGH;
    }
    __syncthreads();
    if (t < 100) {
        float res = 0.0f;
#pragma unroll
        for (int c = 0; c < 32; ++c)
            res += A[c] * sco[c * 100 + t] + B[c] * lino[c * 100 + t];
        out[g * 100 + t] = res * INV_SQRT_NODES;
    }
}

// ================= launcher =================
extern "C" void kernel_launch(void* const* d_in, const int* in_sizes, int n_in,
                              void* d_out, int out_size, void* d_ws, size_t ws_size,
                              hipStream_t stream)
{
    const float* pos   = (const float*)d_in[0];
    const float* x     = (const float*)d_in[1];
    const float* z     = (const float*)d_in[2];
    const int*   ei    = (const int*)d_in[3];
    const float* esh   = (const float*)d_in[4];
    const float* lat   = (const float*)d_in[5];
    const int*   batch = (const int*)d_in[6];
    const float* fc1w0 = (const float*)d_in[7];
    const float* fc1w1 = (const float*)d_in[8];
    const float* sc1   = (const float*)d_in[9];
    const float* lin1s = (const float*)d_in[10];
    const float* lin1v = (const float*)d_in[11];
    const float* fc2w0 = (const float*)d_in[12];
    const float* fc2w1 = (const float*)d_in[13];
    const float* sc2s  = (const float*)d_in[14];
    const float* sc2v  = (const float*)d_in[15];
    const float* lin2s = (const float*)d_in[16];
    const float* lin2v = (const float*)d_in[17];
    const float* fcow0 = (const float*)d_in[18];
    const float* fcow1 = (const float*)d_in[19];
    const float* sco   = (const float*)d_in[20];
    const float* lino  = (const float*)d_in[21];
    float* out = (float*)d_out;

    char* cur = (char*)d_ws;
    auto alloc = [&](size_t bytes) { char* r = cur; cur += (bytes + 15) & ~(size_t)15; return r; };

    float* a1    = (float*)alloc((size_t)NN * 64 * 4);
    float* a2    = (float*)alloc((size_t)NN * 128 * 4);
    float* a3    = (float*)alloc((size_t)NN * 32 * 4);
    float* s2    = (float*)alloc((size_t)NN * 32 * 4);
    unsigned short* row0 = (unsigned short*)alloc((size_t)NN * 16 * 2);
    ushort4* row1 = (ushort4*)alloc((size_t)NN * 32 * 8);
    ushort4* row2 = (ushort4*)alloc((size_t)NN * 32 * 8);
    float* tab1  = (float*)alloc((size_t)NTAB * 32 * 4);
    unsigned short* tab2b = (unsigned short*)alloc((size_t)NTAB * 32 * 8 * 2);
    unsigned short* tab3b = (unsigned short*)alloc((size_t)NTAB * 32 * 2 * 2);
    float* pbuf  = (float*)alloc((size_t)NGRAPHS * SPL * 64 * 4);
    int* deg     = (int*)alloc((size_t)NN * 4);
    int* rowp    = (int*)alloc((size_t)(NN + 4) * 4);
    int* cursor  = (int*)alloc((size_t)NN * 4);
    int* bsum    = (int*)alloc(256 * 4);
    int* boff    = (int*)alloc(256 * 4);
    int* gstart  = (int*)alloc(68 * 4);
    uint4* rec   = (uint4*)alloc((size_t)EE * 16);

    (void)hipMemsetAsync(deg, 0, (size_t)NN * 4, stream);

    k_pre3<<<NTAB + NB_N + NB_E + NB_X, 256, 0, stream>>>(
        fc1w0, fc1w1, fc2w0, fc2w1, fcow0, fcow1, tab1, tab2b, tab3b,
        batch, gstart, ei, deg, x, row0);

    k_scan1<<<NB_N, 256, 0, stream>>>(deg, bsum);
    k_scan2<<<1, 64, 0, stream>>>(bsum, boff, rowp);
    k_scan3<<<NB_N, 256, 0, stream>>>(deg, boff, rowp, cursor);
    k_geom <<<NB_E, 256, 0, stream>>>(pos, ei, esh, lat, batch, cursor, rec);

    int fb = (NN * 64 + 255) / 256;   // 1 wave per node
    k_fuse1<<<fb, 256, 0, stream>>>(rowp, rec, tab1, row0, a1);
    k_node1<<<NB_T, 256, 0, stream>>>(x, z, a1, sc1, lin1s, lin1v, row1);
    k_fuse2<<<fb, 256, 0, stream>>>(rowp, rec, tab2b, (const unsigned short*)row1, a2);
    k_node2<<<NB_T, 256, 0, stream>>>(z, (const uint2*)row1, a2, sc2s, sc2v, lin2s, lin2v, s2, row2);
    k_fuse3<<<fb, 256, 0, stream>>>(rowp, rec, tab3b, (const unsigned short*)row2, a3);
    k_red<<<NGRAPHS * SPL, 256, 0, stream>>>(z, gstart, s2, a3, pbuf);
    k_out2<<<NGRAPHS, 128, 0, stream>>>(pbuf, sco, lino, out);
}

// Round 17
// 359.125 us; speedup vs baseline: 1.1474x; 1.0037x over previous
//
#include <hip/hip_runtime.h>
#include <hip/hip_bf16.h>

#define NN 50000
#define EE 1000000
#define NGRAPHS 64
#define NB_N 196        // (NN+255)/256
#define NB_E 3907       // (EE+255)/256
#define NB_X 3125       // NN*16/256
#define NB_T 1563       // (NN+31)/32 node-tile blocks
#define NTAB 4096
#define SPL 16          // reduction splits per graph

#define INV_SQRT_NEIGH 0.22360679774997896f   // 1/sqrt(20)
#define INV_SQRT_NODES 0.035777087639996634f  // 1/sqrt(781.25)
#define SQRT3 1.7320508075688772f
#define BSCALE 2.8234621879136734f            // sqrt(10)/1.12
#define BSTEP 0.3888888888888889f             // 3.5/9
#define INV_BSTEP 2.5714285714285716f
#define PI_F 3.14159265358979323846f
#define TAB_DR (3.5f / 4095.0f)
#define TAB_SCALE (4095.0f / 3.5f)

typedef float v2f __attribute__((ext_vector_type(2)));

__device__ __forceinline__ float silu_f(float x) { return x / (1.0f + __expf(-x)); }
__device__ __forceinline__ float sigm_f(float x) { return 1.0f / (1.0f + __expf(-x)); }

__device__ __forceinline__ unsigned short f2bf(float f) {
    union { float f; unsigned u; } v; v.f = f;
    unsigned r = v.u + 0x7fffu + ((v.u >> 16) & 1u);
    return (unsigned short)(r >> 16);
}
__device__ __forceinline__ unsigned pk2(float a, float b) {
    return (unsigned)f2bf(a) | ((unsigned)f2bf(b) << 16);
}
__device__ __forceinline__ float bflo(unsigned u) { return __uint_as_float(u << 16); }
__device__ __forceinline__ float bfhi(unsigned u) { return __uint_as_float(u & 0xffff0000u); }

// ================= combined prologue =================
// blocks [0,NTAB): radial tables (block per entry);
// [NTAB, NTAB+NB_N): graph bounds; then degree hist; then x->bf16
__global__ __launch_bounds__(256) void k_pre3(
    const float* __restrict__ fc1w0, const float* __restrict__ fc1w1,
    const float* __restrict__ fc2w0, const float* __restrict__ fc2w1,
    const float* __restrict__ fcow0, const float* __restrict__ fcow1,
    float* __restrict__ tab1, unsigned short* __restrict__ tab2b,
    unsigned short* __restrict__ tab3b,
    const int* __restrict__ batch, int* __restrict__ gstart,
    const int* __restrict__ ei, int* __restrict__ deg,
    const float* __restrict__ x, unsigned short* __restrict__ row0)
{
    int blk = blockIdx.x;
    int t = threadIdx.x;
    if (blk < NTAB) {
        __shared__ float h[3][100];
        int entry = blk;
        float r = entry * TAB_DR;
        float b[10];
#pragma unroll
        for (int i = 0; i < 10; ++i) {
            float d = (r - (float)i * BSTEP) * INV_BSTEP;
            b[i] = __expf(-d * d) * BSCALE;
        }
        for (int job = t; job < 300; job += 256) {
            int tb = job / 100;
            int j = job - tb * 100;
            const float* w0 = (tb == 0) ? fc1w0 : (tb == 1 ? fc2w0 : fcow0);
            float a = 0.0f;
#pragma unroll
            for (int i = 0; i < 10; ++i) a += b[i] * w0[i * 100 + j];
            h[tb][j] = silu_f(a);
        }
        __syncthreads();
        if (t < 32) {
            float acc = 0.0f;
            for (int j = 0; j < 100; ++j) acc += h[0][j] * fc1w1[j * 32 + t];
            tab1[(size_t)entry * 32 + t] = acc;
        } else if (t < 192) {
            int o = t - 32;
            float acc = 0.0f;
            for (int j = 0; j < 100; ++j) acc += h[1][j] * fc2w1[j * 160 + o];
            tab2b[((size_t)entry * 32 + (o & 31)) * 8 + (o >> 5)] = f2bf(acc);
        } else {
            int o = t - 192;
            float acc = 0.0f;
            for (int j = 0; j < 100; ++j) acc += h[2][j] * fcow1[j * 64 + o];
            tab3b[((size_t)entry * 32 + (o & 31)) * 2 + (o >> 5)] = f2bf(acc);
        }
    } else if (blk < NTAB + NB_N) {
        int n = (blk - NTAB) * 256 + t;
        if (n >= NN) return;
        int b = batch[n];
        if (n == 0) { for (int g = 0; g <= b; ++g) gstart[g] = 0; }
        else {
            int pb = batch[n - 1];
            for (int g = pb + 1; g <= b; ++g) gstart[g] = n;
        }
        if (n == NN - 1) { for (int g = b + 1; g <= NGRAPHS; ++g) gstart[g] = NN; }
    } else if (blk < NTAB + NB_N + NB_E) {
        int e = (blk - NTAB - NB_N) * 256 + t;
        if (e < EE) atomicAdd(&deg[ei[EE + e]], 1);
    } else {
        int idx = (blk - NTAB - NB_N - NB_E) * 256 + t;
        if (idx < NN * 16) row0[idx] = f2bf(x[idx]);
    }
}

// ================= CSR scans =================
__global__ __launch_bounds__(256) void k_scan1(const int* __restrict__ deg, int* __restrict__ bsum)
{
    __shared__ int sd[256];
    int t = threadIdx.x;
    int i = blockIdx.x * 256 + t;
    sd[t] = (i < NN) ? deg[i] : 0;
    __syncthreads();
#pragma unroll
    for (int o = 128; o > 0; o >>= 1) {
        if (t < o) sd[t] += sd[t + o];
        __syncthreads();
    }
    if (t == 0) bsum[blockIdx.x] = sd[0];
}

// scan3 with inlined block-offset computation (scan2 merged)
__global__ __launch_bounds__(256) void k_scan3(
    const int* __restrict__ deg, const int* __restrict__ bsum,
    int* __restrict__ rowp, int* __restrict__ cursor)
{
    __shared__ int sd[256];
    __shared__ int boffs;
    int t = threadIdx.x;
    int i = blockIdx.x * 256 + t;
    int v = (i < NN) ? deg[i] : 0;
    sd[t] = v;
    if (t == 0) {
        int acc = 0;
        for (int b = 0; b < (int)blockIdx.x; ++b) acc += bsum[b];
        boffs = acc;
    }
    __syncthreads();
#pragma unroll
    for (int o = 1; o < 256; o <<= 1) {
        int xv = 0;
        if (t >= o) xv = sd[t - o];
        __syncthreads();
        sd[t] += xv;
        __syncthreads();
    }
    if (i < NN) {
        int val = boffs + sd[t] - v;   // exclusive
        rowp[i] = val;
        cursor[i] = val;
    }
    if (i == NN - 1) rowp[NN] = EE;
}

// ---- geometry once per edge, 16B record scattered to dst-sorted slot ----
__global__ __launch_bounds__(256) void k_geom(
    const float* __restrict__ pos, const int* __restrict__ ei,
    const float* __restrict__ eshift, const float* __restrict__ lat,
    const int* __restrict__ batch, int* __restrict__ cursor,
    uint4* __restrict__ rec)
{
    int e = blockIdx.x * 256 + threadIdx.x;
    if (e >= EE) return;
    int src = ei[e];
    int dst = ei[EE + e];
    int g = batch[src];
    const float* L = lat + g * 9;
    float t0 = eshift[e*3+0], t1 = eshift[e*3+1], t2 = eshift[e*3+2];
    float vx = pos[dst*3+0] - pos[src*3+0] + t0*L[0] + t1*L[3] + t2*L[6];
    float vy = pos[dst*3+1] - pos[src*3+1] + t0*L[1] + t1*L[4] + t2*L[7];
    float vz = pos[dst*3+2] - pos[src*3+2] + t0*L[2] + t1*L[5] + t2*L[8];
    float r = sqrtf(vx*vx + vy*vy + vz*vz);
    float u = 2.0f * (r * (1.0f/3.5f) - 1.0f);
    float cut;
    if (u > 0.0f) cut = 0.0f;
    else if (u < -2.0f) cut = 1.0f;
    else cut = 0.5f * (1.0f - __cosf(PI_F * u));
    float inv = 1.0f / fmaxf(r, 1e-12f);
    float sc = SQRT3 * cut * inv;
    int i0 = (int)fminf(r * TAB_SCALE + 0.5f, 4095.0f);
    int slot = atomicAdd(&cursor[dst], 1);
    rec[slot] = make_uint4(pk2(sc * vx, sc * vy), pk2(sc * vz, 0.0f),
                           (unsigned)src | ((unsigned)i0 << 17),
                           __float_as_uint(cut));
}

#define EREC_DECODE(E)                                  \
    float cs_ = __uint_as_float((E).w);                 \
    float cx_ = bflo((E).x);                            \
    float cy_ = bfhi((E).x);                            \
    float cz_ = bflo((E).y);                            \
    int src_ = (int)((E).z & 0x1ffffu);                 \
    int i0_ = (int)((E).z >> 17);

// ================= fused node-centric edge kernels (1 wave = 1 dst node) =================
#define F1_EDGE(E, ACC) {                                           \
    EREC_DECODE(E)                                                  \
    float w_ = tab1[(size_t)i0_ * 32 + toff];                       \
    float xs_ = __uint_as_float((unsigned)row0[src_ * 16 + c] << 16); \
    float gs_ = (q == 0) ? cs_ : (q == 1 ? cx_ : (q == 2 ? cy_ : cz_)); \
    ACC += w_ * xs_ * gs_; }

__global__ __launch_bounds__(256) void k_fuse1(
    const int* __restrict__ rowp, const uint4* __restrict__ rec,
    const float* __restrict__ tab1, const unsigned short* __restrict__ row0,
    float* __restrict__ a1)
{
    int wid = (blockIdx.x * 256 + threadIdx.x) >> 6;
    int l = threadIdx.x & 63;
    if (wid >= NN) return;
    int b0 = __builtin_amdgcn_readfirstlane(rowp[wid]);
    int b1 = __builtin_amdgcn_readfirstlane(rowp[wid + 1]);
    int q = l >> 4, c = l & 15;
    int toff = (q ? 16 : 0) + c;
    float aA = 0.0f, aB = 0.0f, aC = 0.0f, aD = 0.0f;
    int s = b0;
    for (; s + 3 < b1; s += 4) {
        uint4 eA = rec[s], eB = rec[s+1], eC = rec[s+2], eD = rec[s+3];
        F1_EDGE(eA, aA) F1_EDGE(eB, aB) F1_EDGE(eC, aC) F1_EDGE(eD, aD)
    }
    for (; s < b1; ++s) {
        uint4 eA = rec[s];
        F1_EDGE(eA, aA)
    }
    a1[(size_t)wid * 64 + l] = (aA + aB) + (aC + aD);
}

// layer 2: bf16 tab row as ONE uint4; (mx,my) pair + cross product in packed f32
#define F2_EDGE(E, AS, AXY, AZ) {                                   \
    EREC_DECODE(E)                                                  \
    uint4 tv_ = ((const uint4*)tab2b)[(size_t)i0_ * 32 + c];        \
    uint2 rv_ = ((const uint2*)row1)[(size_t)src_ * 32 + c];        \
    float w1_ = bflo(tv_.x), w2_ = bfhi(tv_.x);                     \
    float w3_ = bflo(tv_.y), w4_ = bfhi(tv_.y);                     \
    float w5_ = bflo(tv_.z);                                        \
    float sv_ = bflo(rv_.x), vx_ = bfhi(rv_.x);                     \
    float vy_ = bflo(rv_.y), vz_ = bfhi(rv_.y);                     \
    float dot_ = vx_ * cx_ + vy_ * cy_ + vz_ * cz_;                 \
    float w3s_ = w3_ * sv_, w4c_ = w4_ * cs_;                       \
    AS += w1_ * sv_ * cs_ + w2_ * dot_;                             \
    AZ += w3s_ * cz_ + w4c_ * vz_ + w5_ * (vx_ * cy_ - vy_ * cx_);  \
    v2f cr_ = (v2f){vy_, vz_} * (v2f){cz_, cx_}                     \
            - (v2f){vz_, vx_} * (v2f){cy_, cz_};                    \
    AXY += (v2f){w3s_, w3s_} * (v2f){cx_, cy_}                      \
         + (v2f){w4c_, w4c_} * (v2f){vx_, vy_}                      \
         + (v2f){w5_, w5_} * cr_; }

__global__ __launch_bounds__(256) void k_fuse2(
    const int* __restrict__ rowp, const uint4* __restrict__ rec,
    const unsigned short* __restrict__ tab2b, const unsigned short* __restrict__ row1,
    float* __restrict__ a2)
{
    int wid = (blockIdx.x * 256 + threadIdx.x) >> 6;
    int l = threadIdx.x & 63;
    if (wid >= NN) return;
    int b0 = __builtin_amdgcn_readfirstlane(rowp[wid]);
    int b1 = __builtin_amdgcn_readfirstlane(rowp[wid + 1]);
    int p = l >> 5, c = l & 31;
    float sA = 0.0f, zA = 0.0f, sB = 0.0f, zB = 0.0f;
    v2f xyA = {0.0f, 0.0f}, xyB = {0.0f, 0.0f};
    int s = b0 + p;
    for (; s + 4 < b1; s += 6) {
        uint4 eA = rec[s], eB = rec[s+2], eC = rec[s+4];
        F2_EDGE(eA, sA, xyA, zA)
        F2_EDGE(eB, sB, xyB, zB)
        F2_EDGE(eC, sA, xyA, zA)
    }
    for (; s < b1; s += 2) {
        uint4 eA = rec[s];
        F2_EDGE(eA, sB, xyB, zB)
    }
    float mS = sA + sB, mZ = zA + zB;
    v2f mXY = xyA + xyB;
    float mX = mXY.x, mY = mXY.y;
    mS += __shfl_xor(mS, 32);
    mX += __shfl_xor(mX, 32);
    mY += __shfl_xor(mY, 32);
    mZ += __shfl_xor(mZ, 32);
    if (p == 0) {
        float* ap = a2 + (size_t)wid * 128;
        ap[c]      = mS;
        ap[32 + c] = mX;
        ap[64 + c] = mY;
        ap[96 + c] = mZ;
    }
}

#define F3_EDGE(E, ACC) {                                           \
    EREC_DECODE(E)                                                  \
    unsigned tv_ = ((const unsigned*)tab3b)[(size_t)i0_ * 32 + c];  \
    uint2 rv_ = ((const uint2*)row2)[(size_t)src_ * 32 + c];        \
    float w1_ = bflo(tv_), w2_ = bfhi(tv_);                         \
    float sv_ = bflo(rv_.x), vx_ = bfhi(rv_.x);                     \
    float vy_ = bflo(rv_.y), vz_ = bfhi(rv_.y);                     \
    float dot_ = vx_ * cx_ + vy_ * cy_ + vz_ * cz_;                 \
    ACC += w1_ * sv_ * cs_ + w2_ * dot_; }

__global__ __launch_bounds__(256) void k_fuse3(
    const int* __restrict__ rowp, const uint4* __restrict__ rec,
    const unsigned short* __restrict__ tab3b, const unsigned short* __restrict__ row2,
    float* __restrict__ a3)
{
    int wid = (blockIdx.x * 256 + threadIdx.x) >> 6;
    int l = threadIdx.x & 63;
    if (wid >= NN) return;
    int b0 = __builtin_amdgcn_readfirstlane(rowp[wid]);
    int b1 = __builtin_amdgcn_readfirstlane(rowp[wid + 1]);
    int p = l >> 5, c = l & 31;
    float aA = 0.0f, aB = 0.0f;
    int s = b0 + p;
    for (; s + 6 < b1; s += 8) {
        uint4 eA = rec[s], eB = rec[s+2], eC = rec[s+4], eD = rec[s+6];
        F3_EDGE(eA, aA) F3_EDGE(eB, aB) F3_EDGE(eC, aA) F3_EDGE(eD, aB)
    }
    for (; s < b1; s += 2) {
        uint4 eA = rec[s];
        F3_EDGE(eA, aA)
    }
    float acc = aA + aB;
    acc += __shfl_xor(acc, 32);
    if (p == 0) a3[(size_t)wid * 32 + c] = acc;
}

// ================= node kernels: LDS-tiled, 32 nodes/block, 8 thr/node =================
// a1 layout per node (64 floats): [ms 16][mvx 16][mvy 16][mvz 16]
__global__ __launch_bounds__(256) void k_node1(
    const float* __restrict__ x, const float* __restrict__ z,
    const float* __restrict__ a1,
    const float* __restrict__ sc1, const float* __restrict__ lin1s,
    const float* __restrict__ lin1v,
    ushort4* __restrict__ row1)
{
    __shared__ float xz[32][20];
    __shared__ float am[32][68];
    __shared__ float shb[32][68];
    int t = threadIdx.x;
    int base = blockIdx.x * 32;
    if (t < 128) {
        int node = t >> 2, rem = t & 3;
        if (base + node < NN)
            *(float4*)&xz[node][rem * 4] = ((const float4*)x)[(size_t)(base + node) * 4 + rem];
    }
#pragma unroll
    for (int k = 0; k < 2; ++k) {
        int f = k * 256 + t;
        int node = f >> 4, rem = f & 15;
        if (base + node < NN)
            *(float4*)&am[node][rem * 4] = ((const float4*)a1)[(size_t)(base + node) * 16 + rem];
    }
    __syncthreads();
    int node = t >> 3, og = t & 7;
    int gnode = base + node;
    float zz = (gnode < NN) ? z[gnode] : 0.0f;
    int o0 = og * 8;
    float acc[8];
#pragma unroll
    for (int k = 0; k < 8; ++k) acc[k] = 0.0f;
#pragma unroll
    for (int c = 0; c < 16; ++c) {
        float xc = xz[node][c] * zz;
        float ac = am[node][c] * INV_SQRT_NEIGH;
        float4 wa = *(const float4*)&sc1[c * 64 + o0];
        float4 wb = *(const float4*)&sc1[c * 64 + o0 + 4];
        float4 la = *(const float4*)&lin1s[c * 64 + o0];
        float4 lb = *(const float4*)&lin1s[c * 64 + o0 + 4];
        acc[0] += xc * wa.x + ac * la.x;
        acc[1] += xc * wa.y + ac * la.y;
        acc[2] += xc * wa.z + ac * la.z;
        acc[3] += xc * wa.w + ac * la.w;
        acc[4] += xc * wb.x + ac * lb.x;
        acc[5] += xc * wb.y + ac * lb.y;
        acc[6] += xc * wb.z + ac * lb.z;
        acc[7] += xc * wb.w + ac * lb.w;
    }
#pragma unroll
    for (int k = 0; k < 8; ++k) shb[node][o0 + k] = acc[k];
    __syncthreads();
    int o0v = og * 4;
    float a4[3][4];
#pragma unroll
    for (int i = 0; i < 3; ++i)
#pragma unroll
        for (int k = 0; k < 4; ++k) a4[i][k] = 0.0f;
#pragma unroll
    for (int c = 0; c < 16; ++c) {
        float4 lv = *(const float4*)&lin1v[c * 32 + o0v];
#pragma unroll
        for (int i = 0; i < 3; ++i) {
            float av = am[node][16 + i * 16 + c] * INV_SQRT_NEIGH;
            a4[i][0] += av * lv.x; a4[i][1] += av * lv.y;
            a4[i][2] += av * lv.z; a4[i][3] += av * lv.w;
        }
    }
    if (gnode < NN) {
#pragma unroll
        for (int k = 0; k < 4; ++k) {
            float so = silu_f(shb[node][o0v + k]);
            float gt = sigm_f(shb[node][32 + o0v + k]);
            row1[(size_t)gnode * 32 + o0v + k] =
                make_ushort4(f2bf(so), f2bf(a4[0][k] * gt), f2bf(a4[1][k] * gt), f2bf(a4[2][k] * gt));
        }
    }
}

// a2 layout per node (128 floats): [ms 32][mvx 32][mvy 32][mvz 32]
__global__ __launch_bounds__(256) void k_node2(
    const float* __restrict__ z,
    const uint2* __restrict__ row1, const float* __restrict__ a2,
    const float* __restrict__ sc2s, const float* __restrict__ sc2v,
    const float* __restrict__ lin2s, const float* __restrict__ lin2v,
    float* __restrict__ s2, ushort4* __restrict__ row2)
{
    __shared__ uint2 rw[32][33];
    __shared__ float am[32][132];
    __shared__ float shb[32][68];
    int t = threadIdx.x;
    int base = blockIdx.x * 32;
    {
        int node = t >> 3, rem = t & 7;
        if (base + node < NN) {
            const uint2* rp = row1 + (size_t)(base + node) * 32;
#pragma unroll
            for (int k = 0; k < 4; ++k)
                rw[node][rem * 4 + k] = rp[rem * 4 + k];
        }
    }
#pragma unroll
    for (int k = 0; k < 4; ++k) {
        int f = k * 256 + t;
        int node = f >> 5, rem = f & 31;
        if (base + node < NN)
            *(float4*)&am[node][rem * 4] = ((const float4*)a2)[(size_t)(base + node) * 32 + rem];
    }
    __syncthreads();
    int node = t >> 3, og = t & 7;
    int gnode = base + node;
    float zz = (gnode < NN) ? z[gnode] : 0.0f;
    int o0 = og * 8;
    float acc[8];
#pragma unroll
    for (int k = 0; k < 8; ++k) acc[k] = 0.0f;
#pragma unroll 8
    for (int c = 0; c < 32; ++c) {
        float sv = bflo(rw[node][c].x) * zz;
        float ac = am[node][c] * INV_SQRT_NEIGH;
        float4 wa = *(const float4*)&sc2s[c * 64 + o0];
        float4 wb = *(const float4*)&sc2s[c * 64 + o0 + 4];
        float4 la = *(const float4*)&lin2s[c * 64 + o0];
        float4 lb = *(const float4*)&lin2s[c * 64 + o0 + 4];
        acc[0] += sv * wa.x + ac * la.x;
        acc[1] += sv * wa.y + ac * la.y;
        acc[2] += sv * wa.z + ac * la.z;
        acc[3] += sv * wa.w + ac * la.w;
        acc[4] += sv * wb.x + ac * lb.x;
        acc[5] += sv * wb.y + ac * lb.y;
        acc[6] += sv * wb.z + ac * lb.z;
        acc[7] += sv * wb.w + ac * lb.w;
    }
#pragma unroll
    for (int k = 0; k < 8; ++k) shb[node][o0 + k] = acc[k];
    __syncthreads();
    int o0v = og * 4;
    float a4[3][4];
#pragma unroll
    for (int i = 0; i < 3; ++i)
#pragma unroll
        for (int k = 0; k < 4; ++k) a4[i][k] = 0.0f;
#pragma unroll 8
    for (int c = 0; c < 32; ++c) {
        float4 wv = *(const float4*)&sc2v[c * 32 + o0v];
        float4 lv = *(const float4*)&lin2v[c * 32 + o0v];
        uint2 rv = rw[node][c];
        float vvv[3];
        vvv[0] = bfhi(rv.x); vvv[1] = bflo(rv.y); vvv[2] = bfhi(rv.y);
#pragma unroll
        for (int i = 0; i < 3; ++i) {
            float av = am[node][32 + i * 32 + c] * INV_SQRT_NEIGH;
            a4[i][0] += vvv[i] * wv.x + av * lv.x;
            a4[i][1] += vvv[i] * wv.y + av * lv.y;
            a4[i][2] += vvv[i] * wv.z + av * lv.z;
            a4[i][3] += vvv[i] * wv.w + av * lv.w;
        }
    }
    if (gnode < NN) {
#pragma unroll
        for (int k = 0; k < 4; ++k) {
            float so = silu_f(shb[node][o0v + k]);
            float gt = sigm_f(shb[node][32 + o0v + k]);
            s2[gnode * 32 + o0v + k] = so;
            row2[(size_t)gnode * 32 + o0v + k] =
                make_ushort4(f2bf(so), f2bf(a4[0][k] * gt), f2bf(a4[1][k] * gt), f2bf(a4[2][k] * gt));
        }
    }
}

// ---- output stage 1: per-(graph,split) partial sums of [s2*z | a3] ----
__global__ __launch_bounds__(256) void k_red(
    const float* __restrict__ z, const int* __restrict__ gstart,
    const float* __restrict__ s2, const float* __restrict__ a3,
    float* __restrict__ pbuf)
{
    int g  = blockIdx.x >> 4;      // / SPL
    int sp = blockIdx.x & (SPL - 1);
    int n0 = gstart[g], n1 = gstart[g + 1];
    int per = (n1 - n0 + SPL - 1) / SPL;
    int a = n0 + sp * per;
    int b = a + per; if (b > n1) b = n1;
    int t = threadIdx.x;
    int comp = t & 63;
    int lane = t >> 6;
    float acc = 0.0f;
    for (int n = a + lane; n < b; n += 4) {
        if (comp < 32) acc += s2[n * 32 + comp] * z[n];
        else           acc += a3[(size_t)n * 32 + (comp - 32)];
    }
    __shared__ float sd[256];
    sd[t] = acc;
    __syncthreads();
    if (t < 64)
        pbuf[(size_t)blockIdx.x * 64 + t] = sd[t] + sd[t + 64] + sd[t + 128] + sd[t + 192];
}

// ---- output stage 2: fold partials + (64,32)@(32,100) GEMM ----
__global__ __launch_bounds__(128) void k_out2(
    const float* __restrict__ pbuf, const float* __restrict__ sco,
    const float* __restrict__ lino, float* __restrict__ out)
{
    __shared__ float A[32], B[32];
    int g = blockIdx.x;
    int t = threadIdx.x;
    if (t < 64) {
        float v = 0.0f;
        for (int sp = 0; sp < SPL; ++sp)
            v += pbuf[(size_t)(g * SPL + sp) * 64 + t];
        if (t < 32) A[t] = v;
        else        B[t - 32] = v * INV_SQRT_NEIGH;
    }
    __syncthreads();
    if (t < 100) {
        float res = 0.0f;
#pragma unroll
        for (int c = 0; c < 32; ++c)
            res += A[c] * sco[c * 100 + t] + B[c] * lino[c * 100 + t];
        out[g * 100 + t] = res * INV_SQRT_NODES;
    }
}

// ================= launcher =================
extern "C" void kernel_launch(void* const* d_in, const int* in_sizes, int n_in,
                              void* d_out, int out_size, void* d_ws, size_t ws_size,
                              hipStream_t stream)
{
    const float* pos   = (const float*)d_in[0];
    const float* x     = (const float*)d_in[1];
    const float* z     = (const float*)d_in[2];
    const int*   ei    = (const int*)d_in[3];
    const float* esh   = (const float*)d_in[4];
    const float* lat   = (const float*)d_in[5];
    const int*   batch = (const int*)d_in[6];
    const float* fc1w0 = (const float*)d_in[7];
    const float* fc1w1 = (const float*)d_in[8];
    const float* sc1   = (const float*)d_in[9];
    const float* lin1s = (const float*)d_in[10];
    const float* lin1v = (const float*)d_in[11];
    const float* fc2w0 = (const float*)d_in[12];
    const float* fc2w1 = (const float*)d_in[13];
    const float* sc2s  = (const float*)d_in[14];
    const float* sc2v  = (const float*)d_in[15];
    const float* lin2s = (const float*)d_in[16];
    const float* lin2v = (const float*)d_in[17];
    const float* fcow0 = (const float*)d_in[18];
    const float* fcow1 = (const float*)d_in[19];
    const float* sco   = (const float*)d_in[20];
    const float* lino  = (const float*)d_in[21];
    float* out = (float*)d_out;

    char* cur = (char*)d_ws;
    auto alloc = [&](size_t bytes) { char* r = cur; cur += (bytes + 15) & ~(size_t)15; return r; };

    float* a1    = (float*)alloc((size_t)NN * 64 * 4);
    float* a2    = (float*)alloc((size_t)NN * 128 * 4);
    float* a3    = (float*)alloc((size_t)NN * 32 * 4);
    float* s2    = (float*)alloc((size_t)NN * 32 * 4);
    unsigned short* row0 = (unsigned short*)alloc((size_t)NN * 16 * 2);
    ushort4* row1 = (ushort4*)alloc((size_t)NN * 32 * 8);
    ushort4* row2 = (ushort4*)alloc((size_t)NN * 32 * 8);
    float* tab1  = (float*)alloc((size_t)NTAB * 32 * 4);
    unsigned short* tab2b = (unsigned short*)alloc((size_t)NTAB * 32 * 8 * 2);
    unsigned short* tab3b = (unsigned short*)alloc((size_t)NTAB * 32 * 2 * 2);
    float* pbuf  = (float*)alloc((size_t)NGRAPHS * SPL * 64 * 4);
    int* deg     = (int*)alloc((size_t)NN * 4);
    int* rowp    = (int*)alloc((size_t)(NN + 4) * 4);
    int* cursor  = (int*)alloc((size_t)NN * 4);
    int* bsum    = (int*)alloc(256 * 4);
    int* gstart  = (int*)alloc(68 * 4);
    uint4* rec   = (uint4*)alloc((size_t)EE * 16);

    (void)hipMemsetAsync(deg, 0, (size_t)NN * 4, stream);

    k_pre3<<<NTAB + NB_N + NB_E + NB_X, 256, 0, stream>>>(
        fc1w0, fc1w1, fc2w0, fc2w1, fcow0, fcow1, tab1, tab2b, tab3b,
        batch, gstart, ei, deg, x, row0);

    k_scan1<<<NB_N, 256, 0, stream>>>(deg, bsum);
    k_scan3<<<NB_N, 256, 0, stream>>>(deg, bsum, rowp, cursor);
    k_geom <<<NB_E, 256, 0, stream>>>(pos, ei, esh, lat, batch, cursor, rec);

    int fb = (NN * 64 + 255) / 256;   // 1 wave per node
    k_fuse1<<<fb, 256, 0, stream>>>(rowp, rec, tab1, row0, a1);
    k_node1<<<NB_T, 256, 0, stream>>>(x, z, a1, sc1, lin1s, lin1v, row1);
    k_fuse2<<<fb, 256, 0, stream>>>(rowp, rec, tab2b, (const unsigned short*)row1, a2);
    k_node2<<<NB_T, 256, 0, stream>>>(z, (const uint2*)row1, a2, sc2s, sc2v, lin2s, lin2v, s2, row2);
    k_fuse3<<<fb, 256, 0, stream>>>(rowp, rec, tab3b, (const unsigned short*)row2, a3);
    k_red<<<NGRAPHS * SPL, 256, 0, stream>>>(z, gstart, s2, a3, pbuf);
    k_out2<<<NGRAPHS, 128, 0, stream>>>(pbuf, sco, lino, out);
}